// Round 4
// baseline (402.786 us; speedup 1.0000x reference)
//
#include <hip/hip_runtime.h>

typedef float floatx4 __attribute__((ext_vector_type(4)));
typedef _Float16 half2v __attribute__((ext_vector_type(2)));
typedef _Float16 half8 __attribute__((ext_vector_type(8)));

#define Hh 128
#define Ww 256
#define Cc 64
#define COUT 64
#define Bb 4
#define HW (Hh*Ww)
#define VP 74   // LDS V row stride in shorts: 37 dwords ≡ 5 (mod 32) -> <=2-way (free)

// Combined prep: bx<2 -> x NCHW fp32 -> NHWC fp16 (as before);
// bx==2 -> weight (o,c,kt) fp32 -> fp16 [kt][o][c] (72 elements per block).
__global__ void prep(const float* __restrict__ x, const float* __restrict__ wsrc,
                     _Float16* __restrict__ xn, unsigned short* __restrict__ wdst) {
    const int bx = blockIdx.x, h = blockIdx.y, b = blockIdx.z;
    const int tid = threadIdx.x;
    if (bx == 2) {
        const int i = (h + Hh * b) * 72 + tid;
        if (tid < 72) {   // 512 blocks x 72 = 36864 = 9*64*64
            const int kt = i % 9, c = (i / 9) % Cc, o = i / (9 * Cc);
            _Float16 hv = (_Float16)wsrc[i];
            wdst[(kt * COUT + o) * Cc + c] = *(unsigned short*)&hv;
        }
        return;
    }
    __shared__ unsigned short T[128][VP];
    const int wl = tid & 127;           // position within half-row
    const int ch = tid >> 7;            // channel half (32 ch each)
    const float* sp = x + ((b * Cc + ch * 32) * Hh + h) * Ww + bx * 128 + wl;
#pragma unroll
    for (int c2 = 0; c2 < 16; ++c2) {
        const float v0 = sp[(2 * c2) * HW];
        const float v1 = sp[(2 * c2 + 1) * HW];
        half2v hv; hv.x = (_Float16)v0; hv.y = (_Float16)v1;
        *(unsigned*)&T[wl][ch * 32 + 2 * c2] = *(unsigned*)&hv;
    }
    __syncthreads();
    uint4* drow = (uint4*)(xn + ((size_t)(b * Hh + h) * Ww + bx * 128) * 64);
#pragma unroll
    for (int j = 0; j < 4; ++j) {
        const int idx = j * 256 + tid;        // contiguous 4KB per iteration
        drow[idx] = *(const uint4*)&T[idx >> 3][(idx & 7) * 8];
    }
}

// Raw barrier: lgkmcnt(0) only (LDS visibility), NO vmcnt drain -> in-flight
// global loads survive the barrier.
__device__ __forceinline__ void lds_barrier() {
    asm volatile("s_waitcnt lgkmcnt(0)\n\ts_barrier" ::: "memory");
}

struct Tap {
    half2v W00, W01, W10, W11;   // packed (w,w) fp16 corner weights
    int a00, a01, a10, a11;      // corner addresses in uint4 (16B) units
};

__device__ __forceinline__ void tap_setup(int kt, int h, int w, float dy, float dx,
                                          int cg, Tap& t) {
    const int ki = kt / 3, kj = kt % 3;
    const float py = (float)(h - 1 + ki) + dy;
    const float px = (float)(w - 1 + kj) + dx;
    const float y0f = floorf(py), x0f = floorf(px);
    const int y0 = (int)y0f, x0 = (int)x0f;
    const float ly = py - y0f, lx = px - x0f;
    const int y1 = y0 + 1, x1 = x0 + 1;
    const bool vy0 = ((unsigned)y0 < Hh), vy1 = ((unsigned)y1 < Hh);
    const bool vx0 = ((unsigned)x0 < Ww), vx1 = ((unsigned)x1 < Ww);
    const float w00 = (vy0 && vx0) ? (1.f - ly) * (1.f - lx) : 0.f;
    const float w01 = (vy0 && vx1) ? (1.f - ly) * lx : 0.f;
    const float w10 = (vy1 && vx0) ? ly * (1.f - lx) : 0.f;
    const float w11 = (vy1 && vx1) ? ly * lx : 0.f;
    _Float16 h00 = (_Float16)w00, h01 = (_Float16)w01;
    _Float16 h10 = (_Float16)w10, h11 = (_Float16)w11;
    t.W00.x = h00; t.W00.y = h00;  t.W01.x = h01; t.W01.y = h01;
    t.W10.x = h10; t.W10.y = h10;  t.W11.x = h11; t.W11.y = h11;
    const int y0c = min(max(y0, 0), Hh - 1), y1c = min(max(y1, 0), Hh - 1);
    const int x0c = min(max(x0, 0), Ww - 1), x1c = min(max(x1, 0), Ww - 1);
    t.a00 = (y0c * Ww + x0c) * 8 + cg;   // 8 uint4/pos; cg = 1 uint4 (8ch)
    t.a01 = (y0c * Ww + x1c) * 8 + cg;
    t.a10 = (y1c * Ww + x0c) * 8 + cg;
    t.a11 = (y1c * Ww + x1c) * 8 + cg;
}

__device__ __forceinline__ void tap_load(const uint4* __restrict__ xb4, const Tap& t,
                                         unsigned (&pf)[16]) {
    *(uint4*)&pf[0]  = xb4[t.a00];
    *(uint4*)&pf[4]  = xb4[t.a01];
    *(uint4*)&pf[8]  = xb4[t.a10];
    *(uint4*)&pf[12] = xb4[t.a11];
}

// weight a-fragments for one tap (this wave's 2 m-tiles x 2 k-groups)
__device__ __forceinline__ void wf_load(const unsigned short* __restrict__ wt,
                                        half8 (&WF)[4]) {
    WF[0] = *(const half8*)(wt);                 // g0, mi0
    WF[1] = *(const half8*)(wt + 16 * Cc);       // g0, mi1
    WF[2] = *(const half8*)(wt + 32);            // g1, mi0
    WF[3] = *(const half8*)(wt + 16 * Cc + 32);  // g1, mi1
}

__device__ __forceinline__ void tap_store(const Tap& t, const unsigned (&pf)[16],
                                          unsigned short* __restrict__ vrow) {
    unsigned o[4];
#pragma unroll
    for (int s = 0; s < 4; ++s) {
        half2v v = (*(const half2v*)&pf[s])      * t.W00
                 + (*(const half2v*)&pf[4 + s])  * t.W01
                 + (*(const half2v*)&pf[8 + s])  * t.W10
                 + (*(const half2v*)&pf[12 + s]) * t.W11;
        o[s] = *(unsigned*)&v;
    }
    uint4 u; u.x = o[0]; u.y = o[1]; u.z = o[2]; u.w = o[3];
    *(uint4*)vrow = u;   // single ds_write_b128 (8 channels)
}

__device__ __forceinline__ void mfma_tap(const half8 (&WF)[4],
                                         const unsigned short* __restrict__ Vbuf,
                                         int nt, int ln, floatx4 (&acc)[2]) {
#pragma unroll
    for (int g = 0; g < 2; ++g) {
        const int pp = nt * 16 + (ln & 15);
        half8 bfrag = *(const half8*)&Vbuf[pp * VP + g * 32 + (ln >> 4) * 8];
        acc[0] = __builtin_amdgcn_mfma_f32_16x16x32_f16(WF[2 * g],     bfrag, acc[0], 0, 0, 0);
        acc[1] = __builtin_amdgcn_mfma_f32_16x16x32_f16(WF[2 * g + 1], bfrag, acc[1], 0, 0, 0);
    }
}

// MODE: 0 = full compute (correct output)
//       1 = coalesced-gather ablation (addresses -> (h,w) line; output WRONG,
//           overwritten by the final full dispatch)
//       3 = skeleton ablation (no offset loads / tap_setup / gathers in loop;
//           measures wf_load+MFMA+pack+barrier floor; output WRONG, overwritten)
template<int KT, int MODE>
__device__ __forceinline__ void pipe_iter(
    const uint4* __restrict__ xb4, const float* __restrict__ offb,
    const unsigned short* __restrict__ wfb,
    const unsigned short* __restrict__ V0, const unsigned short* __restrict__ V1,
    unsigned short* __restrict__ vrow0, unsigned short* __restrict__ vrow1,
    int h, int w, int cg, int nt, int ln,
    Tap& tp0, Tap& tp1, unsigned (&pf0)[16], unsigned (&pf1)[16],
    half8 (&WF0)[4], half8 (&WF1)[4],
    float& dy0, float& dx0, float& dy1, float& dx1,
    floatx4 (&acc)[2])
{
    constexpr int S = KT & 1, T = 1 - S;
    // 1. prefetch weight frags for tap KT (consumed next iter / epilogue)
    wf_load(wfb + KT * COUT * Cc, S ? WF1 : WF0);
    if constexpr (MODE != 3) {
        // 2+3. setup & issue gathers for tap KT+1
        if constexpr (KT < 8) {
            tap_setup(KT + 1, h, w, T ? dy1 : dy0, T ? dx1 : dx0, cg, T ? tp1 : tp0);
            if constexpr (MODE == 1) {
                Tap& tt = T ? tp1 : tp0;
                tt.a00 = tt.a01 = tt.a10 = tt.a11 = (h * Ww + w) * 8 + cg;
            }
            tap_load(xb4, T ? tp1 : tp0, T ? pf1 : pf0);
        }
        // 4. offset refill for tap KT+3 (same slot parity as KT+1, just consumed)
        if constexpr (KT + 3 <= 8) {
            (T ? dy1 : dy0) = offb[(2 * (KT + 3)) * HW];
            (T ? dx1 : dx0) = offb[(2 * (KT + 3) + 1) * HW];
        }
    }
    // 5. MFMA tap KT-1 (weights preloaded last iter, V from last iter's store)
    mfma_tap(T ? WF1 : WF0, T ? V1 : V0, nt, ln, acc);
    // 6. combine+pack tap KT into V[KT&1]
    tap_store(S ? tp1 : tp0, S ? pf1 : pf0, S ? vrow1 : vrow0);
    // 7. barrier (lgkm only; VMEM prefetches stay in flight)
    lds_barrier();
}

template<int MODE>
__device__ __forceinline__ void dcn_body(const _Float16* __restrict__ xn,
                                         const float* __restrict__ offset,
                                         const unsigned short* __restrict__ wb,
                                         const float* __restrict__ bias,
                                         float* __restrict__ out) {
    __shared__ unsigned short V[2][32 * VP];   // 2 x 4736 B

    const int tid = threadIdx.x;
    const int p   = tid >> 3;     // position (gather role): 8 lanes share one pos
    const int cg  = tid & 7;      // channel chunk 8ch = 16B
    const int wv  = tid >> 6;     // wave id (MFMA role)
    const int ln  = tid & 63;

    const int b  = blockIdx.z;
    const int h  = blockIdx.y;
    const int w0 = blockIdx.x * 32;
    const int w  = w0 + p;

    const uint4* xb4  = (const uint4*)(xn + (size_t)b * HW * 64);
    const float* offb = offset + b * 18 * HW + h * Ww + w;
    unsigned short* vrow0 = &V[0][p * VP + cg * 8];
    unsigned short* vrow1 = &V[1][p * VP + cg * 8];

    const int nt = wv & 1;
    const int mb = (wv >> 1) * 2;
    // per-wave weight fragment base: o = mb*16 + (ln&15), k-subgroup (ln>>4)*8
    const unsigned short* wfb = wb + (mb * 16 + (ln & 15)) * Cc + (ln >> 4) * 8;

    floatx4 acc[2];
    acc[0] = (floatx4)0.f; acc[1] = (floatx4)0.f;

    unsigned pf0[16], pf1[16];
    half8 WF0[4], WF1[4];
    Tap tp0, tp1;

    // prologue: offsets taps 0..3; WF(0); gathers taps 0,1; store tap 0
    float dy0 = 0.f, dx0 = 0.f, dy1 = 0.f, dx1 = 0.f;
    if constexpr (MODE != 3) {
        dy0 = offb[0];        dx0 = offb[HW];
        dy1 = offb[2 * HW];   dx1 = offb[3 * HW];
    }
    wf_load(wfb, WF0);                        // tap 0 -> WF0
    tap_setup(0, h, w, dy0, dx0, cg, tp0);
    if constexpr (MODE == 1) { tp0.a00 = tp0.a01 = tp0.a10 = tp0.a11 = (h * Ww + w) * 8 + cg; }
    tap_load(xb4, tp0, pf0);
    tap_setup(1, h, w, dy1, dx1, cg, tp1);
    if constexpr (MODE == 1) { tp1.a00 = tp1.a01 = tp1.a10 = tp1.a11 = (h * Ww + w) * 8 + cg; }
    tap_load(xb4, tp1, pf1);
    if constexpr (MODE != 3) {
        dy0 = offb[4 * HW]; dx0 = offb[5 * HW];   // tap 2 -> slot 0
        dy1 = offb[6 * HW]; dx1 = offb[7 * HW];   // tap 3 -> slot 1
    }
    tap_store(tp0, pf0, vrow0);               // waits G(0); G(1) stays in flight
    lds_barrier();

#define PI(K) pipe_iter<K, MODE>(xb4, offb, wfb, V[0], V[1], vrow0, vrow1, h, w, cg, nt, ln, \
                                 tp0, tp1, pf0, pf1, WF0, WF1, dy0, dx0, dy1, dx1, acc)
    PI(1); PI(2); PI(3); PI(4); PI(5); PI(6); PI(7); PI(8);
#undef PI

    // epilogue: tap 8 MFMA (WF0 = tap8 loaded at PI(8), V[0] stored at PI(8))
    mfma_tap(WF0, V[0], nt, ln, acc);

    // epilogue: C/D layout col=lane&15 (pos), row=(lane>>4)*4+reg (o)
    float* outp = out + b * COUT * HW + h * Ww;
    const int col = w0 + nt * 16 + (ln & 15);
#pragma unroll
    for (int mi = 0; mi < 2; ++mi)
#pragma unroll
        for (int r = 0; r < 4; ++r) {
            const int o = (mb + mi) * 16 + (ln >> 4) * 4 + r;
            outp[o * HW + col] = acc[mi][r] + bias[o];
        }
}

// Baseline (anchor, correct output, launched LAST)
__launch_bounds__(256, 4)
__global__ void dcn_full(const _Float16* __restrict__ xn, const float* __restrict__ offset,
                         const unsigned short* __restrict__ wb, const float* __restrict__ bias,
                         float* __restrict__ out) {
    dcn_body<0>(xn, offset, wb, bias, out);
}
// H1 probe: coalesced gather addresses (same instruction stream otherwise)
__launch_bounds__(256, 4)
__global__ void dcn_coal(const _Float16* __restrict__ xn, const float* __restrict__ offset,
                         const unsigned short* __restrict__ wb, const float* __restrict__ bias,
                         float* __restrict__ out) {
    dcn_body<1>(xn, offset, wb, bias, out);
}
// H3 probe: pipeline skeleton (no offset loads / setup / gathers in loop)
__launch_bounds__(256, 4)
__global__ void dcn_skel(const _Float16* __restrict__ xn, const float* __restrict__ offset,
                         const unsigned short* __restrict__ wb, const float* __restrict__ bias,
                         float* __restrict__ out) {
    dcn_body<3>(xn, offset, wb, bias, out);
}
// H4 probe: full compute at 5 waves/SIMD cap (102 VGPR)
__launch_bounds__(256, 5)
__global__ void dcn_lb5(const _Float16* __restrict__ xn, const float* __restrict__ offset,
                        const unsigned short* __restrict__ wb, const float* __restrict__ bias,
                        float* __restrict__ out) {
    dcn_body<0>(xn, offset, wb, bias, out);
}

extern "C" void kernel_launch(void* const* d_in, const int* in_sizes, int n_in,
                              void* d_out, int out_size, void* d_ws, size_t ws_size,
                              hipStream_t stream) {
    const float* x      = (const float*)d_in[0];
    const float* offset = (const float*)d_in[1];
    const float* weight = (const float*)d_in[2];
    const float* bias   = (const float*)d_in[3];
    float* out = (float*)d_out;

    _Float16* xn = (_Float16*)d_ws;                          // 16.8 MiB NHWC fp16
    unsigned short* wb = (unsigned short*)((char*)d_ws + (size_t)Bb * HW * Cc * 2);

    prep<<<dim3(3, Hh, Bb), 256, 0, stream>>>(x, weight, xn, wb);

    const dim3 g(Ww / 32, Hh, Bb), blk(256);
    // Ablation dispatches (outputs overwritten by the final correct dispatch):
    dcn_coal<<<g, blk, 0, stream>>>(xn, offset, wb, bias, out);   // H1: scatter cost
    dcn_skel<<<g, blk, 0, stream>>>(xn, offset, wb, bias, out);   // H3: skeleton floor
    dcn_lb5 <<<g, blk, 0, stream>>>(xn, offset, wb, bias, out);   // H4: occupancy
    // Anchor + the output that gets verified:
    dcn_full<<<g, blk, 0, stream>>>(xn, offset, wb, bias, out);
}

// Round 5
// 178.263 us; speedup vs baseline: 2.2595x; 2.2595x over previous
//
#include <hip/hip_runtime.h>

typedef float floatx4 __attribute__((ext_vector_type(4)));
typedef _Float16 half2v __attribute__((ext_vector_type(2)));
typedef _Float16 half8 __attribute__((ext_vector_type(8)));

#define Hh 128
#define Ww 256
#define Cc 64
#define COUT 64
#define Bb 4
#define HW (Hh*Ww)
#define VP 74   // LDS V row stride in shorts: 37 dwords ≡ 5 (mod 32) -> <=2-way (free)

// Combined prep: bx<2 -> x NCHW fp32 -> NHWC fp16; bx==2 -> weight repack.
// R4 change: phase-1 loads explicitly clustered into a register buffer
// (full MLP: 32 independent HBM streams in flight) before any LDS write.
__global__ void prep(const float* __restrict__ x, const float* __restrict__ wsrc,
                     _Float16* __restrict__ xn, unsigned short* __restrict__ wdst) {
    const int bx = blockIdx.x, h = blockIdx.y, b = blockIdx.z;
    const int tid = threadIdx.x;
    if (bx == 2) {
        const int i = (h + Hh * b) * 72 + tid;
        if (tid < 72) {   // 512 blocks x 72 = 36864 = 9*64*64
            const int kt = i % 9, c = (i / 9) % Cc, o = i / (9 * Cc);
            _Float16 hv = (_Float16)wsrc[i];
            wdst[(kt * COUT + o) * Cc + c] = *(unsigned short*)&hv;
        }
        return;
    }
    __shared__ unsigned short T[128][VP];
    const int wl = tid & 127;           // position within half-row
    const int ch = tid >> 7;            // channel half (32 ch each)
    const float* sp = x + ((b * Cc + ch * 32) * Hh + h) * Ww + bx * 128 + wl;
    float vb[32];
#pragma unroll
    for (int c = 0; c < 32; ++c) vb[c] = sp[c * HW];     // all loads first
#pragma unroll
    for (int c2 = 0; c2 < 16; ++c2) {
        half2v hv; hv.x = (_Float16)vb[2 * c2]; hv.y = (_Float16)vb[2 * c2 + 1];
        *(unsigned*)&T[wl][ch * 32 + 2 * c2] = *(unsigned*)&hv;
    }
    __syncthreads();
    uint4* drow = (uint4*)(xn + ((size_t)(b * Hh + h) * Ww + bx * 128) * 64);
#pragma unroll
    for (int j = 0; j < 4; ++j) {
        const int idx = j * 256 + tid;        // contiguous 4KB per iteration
        drow[idx] = *(const uint4*)&T[idx >> 3][(idx & 7) * 8];
    }
}

// Raw barrier: lgkmcnt(0) only (LDS visibility), NO vmcnt drain -> in-flight
// global loads survive the barrier.
__device__ __forceinline__ void lds_barrier() {
    asm volatile("s_waitcnt lgkmcnt(0)\n\ts_barrier" ::: "memory");
}

struct Tap {
    half2v W00, W01, W10, W11;   // packed (w,w) fp16 corner weights
    int a00, a01, a10, a11;      // corner addresses in uint4 (16B) units
};

// compile-time 3-way selectors (rule #20: never runtime-index register arrays)
template<int I>
__device__ __forceinline__ unsigned (&sel3(unsigned (&a)[16], unsigned (&b)[16],
                                           unsigned (&c)[16]))[16] {
    if constexpr (I == 0) return a; else if constexpr (I == 1) return b; else return c;
}
template<int I>
__device__ __forceinline__ Tap& sel3t(Tap& a, Tap& b, Tap& c) {
    if constexpr (I == 0) return a; else if constexpr (I == 1) return b; else return c;
}

__device__ __forceinline__ void tap_setup(int kt, int h, int w, float dy, float dx,
                                          int cg, Tap& t) {
    const int ki = kt / 3, kj = kt % 3;
    const float py = (float)(h - 1 + ki) + dy;
    const float px = (float)(w - 1 + kj) + dx;
    const float y0f = floorf(py), x0f = floorf(px);
    const int y0 = (int)y0f, x0 = (int)x0f;
    const float ly = py - y0f, lx = px - x0f;
    const int y1 = y0 + 1, x1 = x0 + 1;
    const bool vy0 = ((unsigned)y0 < Hh), vy1 = ((unsigned)y1 < Hh);
    const bool vx0 = ((unsigned)x0 < Ww), vx1 = ((unsigned)x1 < Ww);
    const float w00 = (vy0 && vx0) ? (1.f - ly) * (1.f - lx) : 0.f;
    const float w01 = (vy0 && vx1) ? (1.f - ly) * lx : 0.f;
    const float w10 = (vy1 && vx0) ? ly * (1.f - lx) : 0.f;
    const float w11 = (vy1 && vx1) ? ly * lx : 0.f;
    _Float16 h00 = (_Float16)w00, h01 = (_Float16)w01;
    _Float16 h10 = (_Float16)w10, h11 = (_Float16)w11;
    t.W00.x = h00; t.W00.y = h00;  t.W01.x = h01; t.W01.y = h01;
    t.W10.x = h10; t.W10.y = h10;  t.W11.x = h11; t.W11.y = h11;
    const int y0c = min(max(y0, 0), Hh - 1), y1c = min(max(y1, 0), Hh - 1);
    const int x0c = min(max(x0, 0), Ww - 1), x1c = min(max(x1, 0), Ww - 1);
    t.a00 = (y0c * Ww + x0c) * 8 + cg;   // 8 uint4/pos; cg = 1 uint4 (8ch)
    t.a01 = (y0c * Ww + x1c) * 8 + cg;
    t.a10 = (y1c * Ww + x0c) * 8 + cg;
    t.a11 = (y1c * Ww + x1c) * 8 + cg;
}

__device__ __forceinline__ void tap_load(const uint4* __restrict__ xb4, const Tap& t,
                                         unsigned (&pf)[16]) {
    *(uint4*)&pf[0]  = xb4[t.a00];
    *(uint4*)&pf[4]  = xb4[t.a01];
    *(uint4*)&pf[8]  = xb4[t.a10];
    *(uint4*)&pf[12] = xb4[t.a11];
}

// weight a-fragments for one tap (this wave's 2 m-tiles x 2 k-groups)
__device__ __forceinline__ void wf_load(const unsigned short* __restrict__ wt,
                                        half8 (&WF)[4]) {
    WF[0] = *(const half8*)(wt);                 // g0, mi0
    WF[1] = *(const half8*)(wt + 16 * Cc);       // g0, mi1
    WF[2] = *(const half8*)(wt + 32);            // g1, mi0
    WF[3] = *(const half8*)(wt + 16 * Cc + 32);  // g1, mi1
}

__device__ __forceinline__ void tap_store(const Tap& t, const unsigned (&pf)[16],
                                          unsigned short* __restrict__ vrow) {
    unsigned o[4];
#pragma unroll
    for (int s = 0; s < 4; ++s) {
        half2v v = (*(const half2v*)&pf[s])      * t.W00
                 + (*(const half2v*)&pf[4 + s])  * t.W01
                 + (*(const half2v*)&pf[8 + s])  * t.W10
                 + (*(const half2v*)&pf[12 + s]) * t.W11;
        o[s] = *(unsigned*)&v;
    }
    uint4 u; u.x = o[0]; u.y = o[1]; u.z = o[2]; u.w = o[3];
    *(uint4*)vrow = u;   // single ds_write_b128 (8 channels)
}

__device__ __forceinline__ void mfma_tap(const half8 (&WF)[4],
                                         const unsigned short* __restrict__ Vbuf,
                                         int nt, int ln, floatx4 (&acc)[2]) {
#pragma unroll
    for (int g = 0; g < 2; ++g) {
        const int pp = nt * 16 + (ln & 15);
        half8 bfrag = *(const half8*)&Vbuf[pp * VP + g * 32 + (ln >> 4) * 8];
        acc[0] = __builtin_amdgcn_mfma_f32_16x16x32_f16(WF[2 * g],     bfrag, acc[0], 0, 0, 0);
        acc[1] = __builtin_amdgcn_mfma_f32_16x16x32_f16(WF[2 * g + 1], bfrag, acc[1], 0, 0, 0);
    }
}

// R4: 2-DEEP gather pipeline. Evidence (round-4 ablation): coal≈full (scatter
// pattern free), lb5≈full (occupancy not the lever), VALUBusy 20% (not VALU),
// => cost is vmem WAIT at tap_store with only 1 iter of cover. Fix: issue
// G(KT+2) at iter KT -> 2 full iterations (+2 barriers) of latency cover.
// pf/tp triple-buffered (tap T -> slot T%3), offsets prefetched 4 taps ahead
// (slot by tap parity). VGPR 52 -> ~80, still << 128 cap at (256,4).
template<int KT>
__device__ __forceinline__ void pipe_iter(
    const uint4* __restrict__ xb4, const float* __restrict__ offb,
    const unsigned short* __restrict__ wfb,
    const unsigned short* __restrict__ V0, const unsigned short* __restrict__ V1,
    unsigned short* __restrict__ vrow0, unsigned short* __restrict__ vrow1,
    int h, int w, int cg, int nt, int ln,
    Tap& tpA, Tap& tpB, Tap& tpC,
    unsigned (&pfA)[16], unsigned (&pfB)[16], unsigned (&pfC)[16],
    half8 (&WF0)[4], half8 (&WF1)[4],
    float& dy0, float& dx0, float& dy1, float& dx1,
    floatx4 (&acc)[2])
{
    constexpr int S = KT & 1;        // parity of tap KT (store side)
    // 1. weight frags for tap KT (consumed by mfma at iter KT+1 / epilogue)
    wf_load(wfb + KT * COUT * Cc, S ? WF1 : WF0);
    // 2. setup & issue gathers for tap KT+2 ((KT+2)&1 == S -> offset slot S)
    if constexpr (KT + 2 <= 8) {
        constexpr int GI = (KT + 2) % 3;
        Tap& tg = sel3t<GI>(tpA, tpB, tpC);
        tap_setup(KT + 2, h, w, S ? dy1 : dy0, S ? dx1 : dx0, cg, tg);
        tap_load(xb4, tg, sel3<GI>(pfA, pfB, pfC));
    }
    // 3. offset refill for tap KT+4 into slot S (just consumed by setup above)
    if constexpr (KT + 4 <= 8) {
        (S ? dy1 : dy0) = offb[(2 * (KT + 4)) * HW];
        (S ? dx1 : dx0) = offb[(2 * (KT + 4) + 1) * HW];
    }
    // 4. MFMA tap KT-1 (parity 1-S): weights and V from last iteration
    constexpr int Tm = 1 - S;
    mfma_tap(Tm ? WF1 : WF0, Tm ? V1 : V0, nt, ln, acc);
    // 5. combine+pack tap KT into V[S] (pf/tp slot KT%3, gathered 2 iters ago)
    constexpr int SI = KT % 3;
    tap_store(sel3t<SI>(tpA, tpB, tpC), sel3<SI>(pfA, pfB, pfC),
              S ? vrow1 : vrow0);
    // 6. barrier (lgkm only; VMEM prefetches stay in flight)
    lds_barrier();
}

__launch_bounds__(256, 4)
__global__ void dcn_mfma(const _Float16* __restrict__ xn,   // NHWC fp16
                         const float* __restrict__ offset,
                         const unsigned short* __restrict__ wb,
                         const float* __restrict__ bias,
                         float* __restrict__ out) {
    __shared__ unsigned short V[2][32 * VP];   // 2 x 4736 B

    const int tid = threadIdx.x;
    const int p   = tid >> 3;     // position (gather role): 8 lanes share one pos
    const int cg  = tid & 7;      // channel chunk 8ch = 16B
    const int wv  = tid >> 6;     // wave id (MFMA role)
    const int ln  = tid & 63;

    const int b  = blockIdx.z;
    const int h  = blockIdx.y;
    const int w0 = blockIdx.x * 32;
    const int w  = w0 + p;

    const uint4* xb4  = (const uint4*)(xn + (size_t)b * HW * 64);
    const float* offb = offset + b * 18 * HW + h * Ww + w;
    unsigned short* vrow0 = &V[0][p * VP + cg * 8];
    unsigned short* vrow1 = &V[1][p * VP + cg * 8];

    const int nt = wv & 1;
    const int mb = (wv >> 1) * 2;
    // per-wave weight fragment base: o = mb*16 + (ln&15), k-subgroup (ln>>4)*8
    const unsigned short* wfb = wb + (mb * 16 + (ln & 15)) * Cc + (ln >> 4) * 8;

    floatx4 acc[2];
    acc[0] = (floatx4)0.f; acc[1] = (floatx4)0.f;

    unsigned pfA[16], pfB[16], pfC[16];
    half8 WF0[4], WF1[4];
    Tap tpA, tpB, tpC;

    // prologue: taps 0,1,2 gathered (slots A,B,C); offsets through tap 4.
    float dy0 = offb[0],        dx0 = offb[HW];         // tap0 -> slot0
    float dy1 = offb[2 * HW],   dx1 = offb[3 * HW];     // tap1 -> slot1
    wf_load(wfb, WF0);                                  // WF(0)
    tap_setup(0, h, w, dy0, dx0, cg, tpA);
    tap_load(xb4, tpA, pfA);
    tap_setup(1, h, w, dy1, dx1, cg, tpB);
    tap_load(xb4, tpB, pfB);
    dy0 = offb[4 * HW]; dx0 = offb[5 * HW];             // tap2 -> slot0
    dy1 = offb[6 * HW]; dx1 = offb[7 * HW];             // tap3 -> slot1
    tap_setup(2, h, w, dy0, dx0, cg, tpC);
    tap_load(xb4, tpC, pfC);
    dy0 = offb[8 * HW]; dx0 = offb[9 * HW];             // tap4 -> slot0
    tap_store(tpA, pfA, vrow0);            // waits G(0); G(1),G(2) in flight
    lds_barrier();

#define PI(K) pipe_iter<K>(xb4, offb, wfb, V[0], V[1], vrow0, vrow1, h, w, cg, nt, ln, \
                           tpA, tpB, tpC, pfA, pfB, pfC, WF0, WF1,                     \
                           dy0, dx0, dy1, dx1, acc)
    PI(1); PI(2); PI(3); PI(4); PI(5); PI(6); PI(7); PI(8);
#undef PI

    // epilogue: tap 8 MFMA (WF0 = tap8 loaded at PI(8), V[0] stored at PI(8))
    mfma_tap(WF0, V[0], nt, ln, acc);

    // epilogue: C/D layout col=lane&15 (pos), row=(lane>>4)*4+reg (o)
    float* outp = out + b * COUT * HW + h * Ww;
    const int col = w0 + nt * 16 + (ln & 15);
#pragma unroll
    for (int mi = 0; mi < 2; ++mi)
#pragma unroll
        for (int r = 0; r < 4; ++r) {
            const int o = (mb + mi) * 16 + (ln >> 4) * 4 + r;
            outp[o * HW + col] = acc[mi][r] + bias[o];
        }
}

extern "C" void kernel_launch(void* const* d_in, const int* in_sizes, int n_in,
                              void* d_out, int out_size, void* d_ws, size_t ws_size,
                              hipStream_t stream) {
    const float* x      = (const float*)d_in[0];
    const float* offset = (const float*)d_in[1];
    const float* weight = (const float*)d_in[2];
    const float* bias   = (const float*)d_in[3];
    float* out = (float*)d_out;

    _Float16* xn = (_Float16*)d_ws;                          // 16.8 MiB NHWC fp16
    unsigned short* wb = (unsigned short*)((char*)d_ws + (size_t)Bb * HW * Cc * 2);

    prep<<<dim3(3, Hh, Bb), 256, 0, stream>>>(x, weight, xn, wb);
    dcn_mfma<<<dim3(Ww / 32, Hh, Bb), 256, 0, stream>>>(xn, offset, wb, bias, out);
}

// Round 6
// 143.015 us; speedup vs baseline: 2.8164x; 1.2465x over previous
//
#include <hip/hip_runtime.h>

typedef float floatx4 __attribute__((ext_vector_type(4)));
typedef _Float16 half2v __attribute__((ext_vector_type(2)));
typedef _Float16 half8 __attribute__((ext_vector_type(8)));

#define Hh 128
#define Ww 256
#define Cc 64
#define COUT 64
#define Bb 4
#define HW (Hh*Ww)
#define VP 74   // LDS V row stride in shorts: 37 dwords ≡ 5 (mod 32) -> <=2-way (free)

// R6 prep rewrite. Theory: old prep (84 µs, 600 GB/s) was DRAM-granule-bound:
// each wave-instr read 256B then jumped 128KB (49K scattered 256B granules).
// New: block = (cg, T=(b,ht)) stages 8 ch x 8 h-rows; phase-1 streams 8
// contiguous 8KB runs (1KB/instr); phase-2 emits NHWC 16B c-slices.
// XCD swizzle: bid = cg*64 + T, 64%8==0 => xcd = T%8 for ALL cg => the 8
// interleaved 16B slices of each 128B output line merge in ONE L2 (no
// cross-XCD write amplification).
// Blocks >= 512: weight repack into FRAGMENT-MAJOR layout for dcn:
// [kt][mbh][j][ln][8]  (j = g*2+mi, ln = ksub*16 + r) -> each wf_load instr
// is 64 lanes x contiguous 16B = 8 lines (was 16 lines at 50% waste).
__launch_bounds__(512, 4)
__global__ void prep(const float* __restrict__ x, const float* __restrict__ wsrc,
                     _Float16* __restrict__ xn, unsigned short* __restrict__ wdst) {
    const int bid = blockIdx.x;
    const int tid = threadIdx.x;
    if (bid >= 512) {   // weight repack: 512 blocks x 72 elems
        const int i = (bid - 512) * 72 + tid;
        if (tid < 72) { // i = o*576 + c*9 + kt
            const int kt = i % 9, c = (i / 9) % Cc, o = i / (9 * Cc);
            const int mbh = o >> 5, mi = (o >> 4) & 1, r = o & 15;
            const int g = c >> 5, ks = (c >> 3) & 3, s = c & 7;
            const int ln = ks * 16 + r, j = g * 2 + mi;
            _Float16 hv = (_Float16)wsrc[i];
            wdst[(((kt * 2 + mbh) * 4 + j) * 64 + ln) * 8 + s] = *(unsigned short*)&hv;
        }
        return;
    }
    const int cg = bid >> 6;          // channel group (8 ch)
    const int T  = bid & 63;          // tile
    const int b  = T >> 4;
    const int ht = T & 15;            // 8-row h tile
    // [c*8+hh][w] fp32; row stride 260 dwords: 16B-aligned rows (1040B) and
    // phase-2 column reads land 2-way on banks (free).
    __shared__ float Tf[64][260];
    const float* src = x + ((size_t)(b * Cc + cg * 8) * Hh + ht * 8) * Ww;
    // phase 1: 8 sweeps x dwordx4; each wave-instr = 1KB contiguous; each
    // (c,hh) stream = 8KB contiguous in x.
#pragma unroll
    for (int s = 0; s < 8; ++s) {
        const int u   = s * 512 + tid;      // 16B-unit index in [0,4096)
        const int row = u >> 6;             // c*8 + hh
        const int wq  = u & 63;
        const float4 v = *(const float4*)(src + (size_t)(row >> 3) * HW + (row & 7) * Ww + wq * 4);
        *(float4*)&Tf[row][wq * 4] = v;
    }
    __syncthreads();
    // phase 2: 4 iters: 8 column reads (bank 2-way = free) -> fp16x8 -> 16B store
#pragma unroll
    for (int j2 = 0; j2 < 4; ++j2) {
        const int idx = j2 * 512 + tid;     // hh*256 + w
        const int hh = idx >> 8, w = idx & 255;
        unsigned o4[4];
#pragma unroll
        for (int cp = 0; cp < 4; ++cp) {
            half2v hv;
            hv.x = (_Float16)Tf[(2 * cp) * 8 + hh][w];
            hv.y = (_Float16)Tf[(2 * cp + 1) * 8 + hh][w];
            o4[cp] = *(unsigned*)&hv;
        }
        uint4 u4; u4.x = o4[0]; u4.y = o4[1]; u4.z = o4[2]; u4.w = o4[3];
        *(uint4*)(xn + ((size_t)(b * Hh + ht * 8 + hh) * Ww + w) * 64 + cg * 8) = u4;
    }
}

// Raw barrier: lgkmcnt(0) only (LDS visibility), NO vmcnt drain -> in-flight
// global loads survive the barrier.
__device__ __forceinline__ void lds_barrier() {
    asm volatile("s_waitcnt lgkmcnt(0)\n\ts_barrier" ::: "memory");
}

struct Tap {
    half2v W00, W01, W10, W11;   // packed (w,w) fp16 corner weights
    int a00, a01, a10, a11;      // corner addresses in uint4 (16B) units
};

// compile-time 3-way selectors (rule #20: never runtime-index register arrays)
template<int I>
__device__ __forceinline__ unsigned (&sel3(unsigned (&a)[16], unsigned (&b)[16],
                                           unsigned (&c)[16]))[16] {
    if constexpr (I == 0) return a; else if constexpr (I == 1) return b; else return c;
}
template<int I>
__device__ __forceinline__ Tap& sel3t(Tap& a, Tap& b, Tap& c) {
    if constexpr (I == 0) return a; else if constexpr (I == 1) return b; else return c;
}

__device__ __forceinline__ void tap_setup(int kt, int h, int w, float dy, float dx,
                                          int cg, Tap& t) {
    const int ki = kt / 3, kj = kt % 3;
    const float py = (float)(h - 1 + ki) + dy;
    const float px = (float)(w - 1 + kj) + dx;
    const float y0f = floorf(py), x0f = floorf(px);
    const int y0 = (int)y0f, x0 = (int)x0f;
    const float ly = py - y0f, lx = px - x0f;
    const int y1 = y0 + 1, x1 = x0 + 1;
    const bool vy0 = ((unsigned)y0 < Hh), vy1 = ((unsigned)y1 < Hh);
    const bool vx0 = ((unsigned)x0 < Ww), vx1 = ((unsigned)x1 < Ww);
    const float w00 = (vy0 && vx0) ? (1.f - ly) * (1.f - lx) : 0.f;
    const float w01 = (vy0 && vx1) ? (1.f - ly) * lx : 0.f;
    const float w10 = (vy1 && vx0) ? ly * (1.f - lx) : 0.f;
    const float w11 = (vy1 && vx1) ? ly * lx : 0.f;
    _Float16 h00 = (_Float16)w00, h01 = (_Float16)w01;
    _Float16 h10 = (_Float16)w10, h11 = (_Float16)w11;
    t.W00.x = h00; t.W00.y = h00;  t.W01.x = h01; t.W01.y = h01;
    t.W10.x = h10; t.W10.y = h10;  t.W11.x = h11; t.W11.y = h11;
    const int y0c = min(max(y0, 0), Hh - 1), y1c = min(max(y1, 0), Hh - 1);
    const int x0c = min(max(x0, 0), Ww - 1), x1c = min(max(x1, 0), Ww - 1);
    t.a00 = (y0c * Ww + x0c) * 8 + cg;   // 8 uint4/pos; cg = 1 uint4 (8ch)
    t.a01 = (y0c * Ww + x1c) * 8 + cg;
    t.a10 = (y1c * Ww + x0c) * 8 + cg;
    t.a11 = (y1c * Ww + x1c) * 8 + cg;
}

__device__ __forceinline__ void tap_load(const uint4* __restrict__ xb4, const Tap& t,
                                         unsigned (&pf)[16]) {
    *(uint4*)&pf[0]  = xb4[t.a00];
    *(uint4*)&pf[4]  = xb4[t.a01];
    *(uint4*)&pf[8]  = xb4[t.a10];
    *(uint4*)&pf[12] = xb4[t.a11];
}

// weight a-fragments, fragment-major layout: 4 x contiguous-1KB wave loads.
__device__ __forceinline__ void wf_load(const unsigned short* __restrict__ wt,
                                        half8 (&WF)[4]) {
    WF[0] = *(const half8*)(wt);             // j0 = (g0, mi0)
    WF[1] = *(const half8*)(wt + 512);       // j1 = (g0, mi1)
    WF[2] = *(const half8*)(wt + 1024);      // j2 = (g1, mi0)
    WF[3] = *(const half8*)(wt + 1536);      // j3 = (g1, mi1)
}

__device__ __forceinline__ void tap_store(const Tap& t, const unsigned (&pf)[16],
                                          unsigned short* __restrict__ vrow) {
    unsigned o[4];
#pragma unroll
    for (int s = 0; s < 4; ++s) {
        half2v v = (*(const half2v*)&pf[s])      * t.W00
                 + (*(const half2v*)&pf[4 + s])  * t.W01
                 + (*(const half2v*)&pf[8 + s])  * t.W10
                 + (*(const half2v*)&pf[12 + s]) * t.W11;
        o[s] = *(unsigned*)&v;
    }
    uint4 u; u.x = o[0]; u.y = o[1]; u.z = o[2]; u.w = o[3];
    *(uint4*)vrow = u;   // single ds_write_b128 (8 channels)
}

__device__ __forceinline__ void mfma_tap(const half8 (&WF)[4],
                                         const unsigned short* __restrict__ Vbuf,
                                         int nt, int ln, floatx4 (&acc)[2]) {
#pragma unroll
    for (int g = 0; g < 2; ++g) {
        const int pp = nt * 16 + (ln & 15);
        half8 bfrag = *(const half8*)&Vbuf[pp * VP + g * 32 + (ln >> 4) * 8];
        acc[0] = __builtin_amdgcn_mfma_f32_16x16x32_f16(WF[2 * g],     bfrag, acc[0], 0, 0, 0);
        acc[1] = __builtin_amdgcn_mfma_f32_16x16x32_f16(WF[2 * g + 1], bfrag, acc[1], 0, 0, 0);
    }
}

// 2-deep gather pipeline (R4; neutral but verified). R6 change: weight loads
// now contiguous (see wf_load) -> weight TA line-traffic halved per tap.
template<int KT>
__device__ __forceinline__ void pipe_iter(
    const uint4* __restrict__ xb4, const float* __restrict__ offb,
    const unsigned short* __restrict__ wfb,
    const unsigned short* __restrict__ V0, const unsigned short* __restrict__ V1,
    unsigned short* __restrict__ vrow0, unsigned short* __restrict__ vrow1,
    int h, int w, int cg, int nt, int ln,
    Tap& tpA, Tap& tpB, Tap& tpC,
    unsigned (&pfA)[16], unsigned (&pfB)[16], unsigned (&pfC)[16],
    half8 (&WF0)[4], half8 (&WF1)[4],
    float& dy0, float& dx0, float& dy1, float& dx1,
    floatx4 (&acc)[2])
{
    constexpr int S = KT & 1;        // parity of tap KT (store side)
    // 1. weight frags for tap KT (fragment-major: KT*4096 shorts)
    wf_load(wfb + KT * 4096, S ? WF1 : WF0);
    // 2. setup & issue gathers for tap KT+2 ((KT+2)&1 == S -> offset slot S)
    if constexpr (KT + 2 <= 8) {
        constexpr int GI = (KT + 2) % 3;
        Tap& tg = sel3t<GI>(tpA, tpB, tpC);
        tap_setup(KT + 2, h, w, S ? dy1 : dy0, S ? dx1 : dx0, cg, tg);
        tap_load(xb4, tg, sel3<GI>(pfA, pfB, pfC));
    }
    // 3. offset refill for tap KT+4 into slot S
    if constexpr (KT + 4 <= 8) {
        (S ? dy1 : dy0) = offb[(2 * (KT + 4)) * HW];
        (S ? dx1 : dx0) = offb[(2 * (KT + 4) + 1) * HW];
    }
    // 4. MFMA tap KT-1 (parity 1-S): weights and V from last iteration
    constexpr int Tm = 1 - S;
    mfma_tap(Tm ? WF1 : WF0, Tm ? V1 : V0, nt, ln, acc);
    // 5. combine+pack tap KT into V[S] (pf/tp slot KT%3, gathered 2 iters ago)
    constexpr int SI = KT % 3;
    tap_store(sel3t<SI>(tpA, tpB, tpC), sel3<SI>(pfA, pfB, pfC),
              S ? vrow1 : vrow0);
    // 6. barrier (lgkm only; VMEM prefetches stay in flight)
    lds_barrier();
}

__launch_bounds__(256, 4)
__global__ void dcn_mfma(const _Float16* __restrict__ xn,   // NHWC fp16
                         const float* __restrict__ offset,
                         const unsigned short* __restrict__ wb,
                         const float* __restrict__ bias,
                         float* __restrict__ out) {
    __shared__ unsigned short V[2][32 * VP];   // 2 x 4736 B

    const int tid = threadIdx.x;
    const int p   = tid >> 3;     // position (gather role): 8 lanes share one pos
    const int cg  = tid & 7;      // channel chunk 8ch = 16B
    const int wv  = tid >> 6;     // wave id (MFMA role)
    const int ln  = tid & 63;

    const int b  = blockIdx.z;
    const int h  = blockIdx.y;
    const int w0 = blockIdx.x * 32;
    const int w  = w0 + p;

    const uint4* xb4  = (const uint4*)(xn + (size_t)b * HW * 64);
    const float* offb = offset + b * 18 * HW + h * Ww + w;
    unsigned short* vrow0 = &V[0][p * VP + cg * 8];
    unsigned short* vrow1 = &V[1][p * VP + cg * 8];

    const int nt = wv & 1;
    const int mb = (wv >> 1) * 2;
    // fragment-major weight base: region (mbh = wv>>1) + lane offset
    const unsigned short* wfb = wb + (wv >> 1) * 2048 + ln * 8;

    floatx4 acc[2];
    acc[0] = (floatx4)0.f; acc[1] = (floatx4)0.f;

    unsigned pfA[16], pfB[16], pfC[16];
    half8 WF0[4], WF1[4];
    Tap tpA, tpB, tpC;

    // prologue: taps 0,1,2 gathered (slots A,B,C); offsets through tap 4.
    float dy0 = offb[0],        dx0 = offb[HW];         // tap0 -> slot0
    float dy1 = offb[2 * HW],   dx1 = offb[3 * HW];     // tap1 -> slot1
    wf_load(wfb, WF0);                                  // WF(0)
    tap_setup(0, h, w, dy0, dx0, cg, tpA);
    tap_load(xb4, tpA, pfA);
    tap_setup(1, h, w, dy1, dx1, cg, tpB);
    tap_load(xb4, tpB, pfB);
    dy0 = offb[4 * HW]; dx0 = offb[5 * HW];             // tap2 -> slot0
    dy1 = offb[6 * HW]; dx1 = offb[7 * HW];             // tap3 -> slot1
    tap_setup(2, h, w, dy0, dx0, cg, tpC);
    tap_load(xb4, tpC, pfC);
    dy0 = offb[8 * HW]; dx0 = offb[9 * HW];             // tap4 -> slot0
    tap_store(tpA, pfA, vrow0);            // waits G(0); G(1),G(2) in flight
    lds_barrier();

#define PI(K) pipe_iter<K>(xb4, offb, wfb, V[0], V[1], vrow0, vrow1, h, w, cg, nt, ln, \
                           tpA, tpB, tpC, pfA, pfB, pfC, WF0, WF1,                     \
                           dy0, dx0, dy1, dx1, acc)
    PI(1); PI(2); PI(3); PI(4); PI(5); PI(6); PI(7); PI(8);
#undef PI

    // epilogue: tap 8 MFMA (WF0 = tap8 loaded at PI(8), V[0] stored at PI(8))
    mfma_tap(WF0, V[0], nt, ln, acc);

    // epilogue: C/D layout col=lane&15 (pos), row=(lane>>4)*4+reg (o)
    float* outp = out + b * COUT * HW + h * Ww;
    const int col = w0 + nt * 16 + (ln & 15);
#pragma unroll
    for (int mi = 0; mi < 2; ++mi)
#pragma unroll
        for (int r = 0; r < 4; ++r) {
            const int o = (mb + mi) * 16 + (ln >> 4) * 4 + r;
            outp[o * HW + col] = acc[mi][r] + bias[o];
        }
}

extern "C" void kernel_launch(void* const* d_in, const int* in_sizes, int n_in,
                              void* d_out, int out_size, void* d_ws, size_t ws_size,
                              hipStream_t stream) {
    const float* x      = (const float*)d_in[0];
    const float* offset = (const float*)d_in[1];
    const float* weight = (const float*)d_in[2];
    const float* bias   = (const float*)d_in[3];
    float* out = (float*)d_out;

    _Float16* xn = (_Float16*)d_ws;                          // 16.8 MiB NHWC fp16
    unsigned short* wb = (unsigned short*)((char*)d_ws + (size_t)Bb * HW * Cc * 2);

    prep<<<dim3(1024), 512, 0, stream>>>(x, weight, xn, wb);
    dcn_mfma<<<dim3(Ww / 32, Hh, Bb), 256, 0, stream>>>(xn, offset, wb, bias, out);
}